// Round 7
// baseline (472.819 us; speedup 1.0000x reference)
//
#include <hip/hip_runtime.h>
#include <hip/hip_bf16.h>

#define N_NODES 50000
#define N_EDGES 500000
#define DIM_A 128
#define DIM_V 32
#define CHAN 32
#define EB 64            // edges per block in edge kernel
#define SCAN_B 49        // ceil(50000/1024)

typedef __attribute__((ext_vector_type(8))) short short8;
typedef __attribute__((ext_vector_type(8))) unsigned short ushort8;
typedef __attribute__((ext_vector_type(4))) float f32x4;
typedef unsigned short ushort;

#define MFMA __builtin_amdgcn_mfma_f32_16x16x32_bf16

__device__ __forceinline__ ushort f2bf(float x) {
    __hip_bfloat16 h = __float2bfloat16(x);
    return *reinterpret_cast<ushort*>(&h);
}
__device__ __forceinline__ float bf2f(ushort u) {
    union { float f; unsigned int i; } v; v.i = ((unsigned int)u) << 16; return v.f;
}
__device__ __forceinline__ float leaky(float x) {
    return x >= 0.f ? x : 0.1f * x;
}
// pack 4 f32 -> 4 bf16 (2 dwords) with the SAME conversion as f2bf (RNE,
// bit-exact vs the v5 scalar path). Compiler may fuse to v_cvt_pk; even if
// not, the win is the ds_write_b64 (1 LDS op per 4 values instead of 4).
__device__ __forceinline__ uint2 pk4(f32x4 v) {
    uint2 r;
    r.x = (unsigned)f2bf(v[0]) | ((unsigned)f2bf(v[1]) << 16);
    r.y = (unsigned)f2bf(v[2]) | ((unsigned)f2bf(v[3]) << 16);
    return r;
}

// ---------------- fused prep: convw + node_proj + hist ----------------------
// Fragment packing: element W[o][c] (o = output col, c = K index) lives at
//   ushort idx = ((o>>4)*KB + (c>>5))*512 + ((c>>3)&3)*128 + (o&15)*8 + (c&7)
// so a wave's fragment (fixed nt=o>>4, kb=c>>5) is the contiguous 1KB chunk
//   frag_short8[ (nt*KB+kb)*64 + lane ]
__global__ __launch_bounds__(256) void prep_kernel(
    const float* __restrict__ x_a, const float* __restrict__ x_v,
    const float* __restrict__ W_L0, const float* __restrict__ W_L1,
    const int* __restrict__ src,
    const float* __restrict__ Wy000, const float* __restrict__ Wy110,
    const float* __restrict__ Wy011, const float* __restrict__ Wy101,
    const float* __restrict__ Wy111,
    const float* __restrict__ Wm1, const float* __restrict__ Wm2,
    const float* __restrict__ Wm3,
    float* __restrict__ LN, int* __restrict__ degS,
    ushort* __restrict__ W0b, ushort* __restrict__ Wm1b,
    ushort* __restrict__ Wm2b, ushort* __restrict__ Wm3b,
    ushort* __restrict__ W011b, ushort* __restrict__ W101b,
    ushort* __restrict__ W111b)
{
    const int t = threadIdx.x;
    const int g = blockIdx.x * 256 + t;

    // --- histogram ---
    if (g < N_EDGES) atomicAdd(&degS[src[g]], 1);

    // --- weight conversion (blocks 0..63) ---
    if (g < 128 * 128) {          // [128][128] matrices, KB=4
        int o = g >> 7, c = g & 127;
        int pi = ((o >> 4) * 4 + (c >> 5)) * 512 + ((c >> 3) & 3) * 128
               + (o & 15) * 8 + (c & 7);
        Wm1b[pi] = f2bf(Wm1[g]);
        Wm2b[pi] = f2bf(Wm2[g]);
        Wm3b[pi] = f2bf(Wm3[g]);
    }
    if (g < 128 * 64) {           // W0cat [128][64], KB=2; c<32 Wy000 else Wy110
        int o = g >> 6, c = g & 63;
        float v = (c < 32) ? Wy000[o * 32 + c] : Wy110[o * 32 + (c - 32)];
        int pi = ((o >> 4) * 2 + (c >> 5)) * 512 + ((c >> 3) & 3) * 128
               + (o & 15) * 8 + (c & 7);
        W0b[pi] = f2bf(v);
    }
    if (g < 32 * 32) {            // [32][32] matrices, KB=1
        int o = g >> 5, c = g & 31;
        int pi = (o >> 4) * 512 + ((c >> 3) & 3) * 128 + (o & 15) * 8 + (c & 7);
        W011b[pi] = f2bf(Wy011[g]);
        W101b[pi] = f2bf(Wy101[g]);
        W111b[pi] = f2bf(Wy111[g]);
    }

    // --- node projection: LN[n][128] = [L0(32) | L1(96, c*3+i)] ---
    const int n = blockIdx.x * 8 + (t >> 5);
    const int c = t & 31;

    const float4* xa = (const float4*)(x_a + (size_t)n * DIM_A);
    const float4* w0 = (const float4*)(W_L0 + c * DIM_A);
    float acc = 0.f;
#pragma unroll 8
    for (int k = 0; k < DIM_A / 4; ++k) {
        float4 x = xa[k]; float4 w = w0[k];
        acc += x.x * w.x + x.y * w.y + x.z * w.z + x.w * w.w;
    }
    LN[(size_t)n * 128 + c] = acc;

    // vectorized x_v / W_L1: 4 d-values (12 floats) per step
    const float4* xv4 = (const float4*)(x_v + (size_t)n * DIM_V * 3);
    const float4* w14 = (const float4*)(W_L1 + c * DIM_V);
    float a0 = 0.f, a1 = 0.f, a2 = 0.f;
#pragma unroll
    for (int dd = 0; dd < DIM_V / 4; ++dd) {
        float4 wv = w14[dd];
        float4 f0 = xv4[dd * 3 + 0];
        float4 f1 = xv4[dd * 3 + 1];
        float4 f2 = xv4[dd * 3 + 2];
        a0 += wv.x * f0.x + wv.y * f0.w + wv.z * f1.z + wv.w * f2.y;
        a1 += wv.x * f0.y + wv.y * f1.x + wv.z * f1.w + wv.w * f2.z;
        a2 += wv.x * f0.z + wv.y * f1.y + wv.z * f2.x + wv.w * f2.w;
    }
    float* o = LN + (size_t)n * 128 + 32 + c * 3;
    o[0] = a0; o[1] = a1; o[2] = a2;
}

// ---------------- scan phase 1: per-1024-block inclusive scan ---------------
__global__ __launch_bounds__(1024) void scan1_kernel(const int* __restrict__ deg,
                                                     int* __restrict__ excl,
                                                     int* __restrict__ bsum)
{
    __shared__ int buf[1024];
    int t = threadIdx.x;
    int i = blockIdx.x * 1024 + t;
    int v = (i < N_NODES) ? deg[i] : 0;
    buf[t] = v;
    __syncthreads();
    for (int off = 1; off < 1024; off <<= 1) {
        int x = (t >= off) ? buf[t - off] : 0;
        __syncthreads();
        buf[t] += x;
        __syncthreads();
    }
    if (i < N_NODES) excl[i] = buf[t] - v;
    if (t == 1023) bsum[blockIdx.x] = buf[1023];
}

// ---------------- scan phase 2: add bsum prefix -> cursor; zero d_out -------
__global__ __launch_bounds__(1024) void scan3_kernel(const int* __restrict__ excl,
                                                     const int* __restrict__ bsum,
                                                     int* __restrict__ cursor,
                                                     f32x4* __restrict__ out4,
                                                     int total4)
{
    __shared__ int sOff;
    int t = threadIdx.x;
    if (t == 0) {
        int s = 0;
#pragma unroll
        for (int k = 0; k < SCAN_B; ++k)
            s += (k < blockIdx.x) ? bsum[k] : 0;
        sOff = s;
    }
    // zero output while the prefix load resolves
    f32x4 z = {0.f, 0.f, 0.f, 0.f};
    for (int i = blockIdx.x * 1024 + t; i < total4; i += SCAN_B * 1024)
        __builtin_nontemporal_store(z, out4 + i);
    __syncthreads();
    int i = blockIdx.x * 1024 + t;
    if (i < N_NODES) cursor[i] = excl[i] + sOff;
}

// ---------------- scatter: build src-sorted packed edge records -------------
__global__ __launch_bounds__(256) void scatter_kernel(
    const int* __restrict__ src, const int* __restrict__ dst,
    const float* __restrict__ r_ij, int* __restrict__ curS,
    float4* __restrict__ edgeS, int* __restrict__ srcIdS)
{
    int i = blockIdx.x * 256 + threadIdx.x;
    if (i < N_EDGES) {
        int s = src[i];
        int p = atomicAdd(&curS[s], 1);
        edgeS[p] = make_float4(r_ij[i * 3 + 0], r_ij[i * 3 + 1], r_ij[i * 3 + 2],
                               __int_as_float(dst[i]));
        srcIdS[p] = s;
    }
}

// ---------------- MFMA edge kernel, fused segmented reduction ---------------
// v6b: operand-swapped MFMAs (W @ act^T) -> thread holds 4 consecutive
// channels of ONE edge; store phases use packed ds_write_b64 (pk4 = bit-exact
// f2bf packing, NOT the cvt_pk asm that v6 used). A/B layout symmetry is
// guaranteed by v5's correctness (any common (lane,j)->k permutation cancels).
// LDS exactly 40960 B: sY0 9216 + sRELV 13312 + sACT 17408 + sRS 1024.
__global__ __launch_bounds__(256, 4) void edge_mfma_kernel(
    const float4* __restrict__ edgeS, const int* __restrict__ srcIdS,
    const float* __restrict__ LN,
    const float* __restrict__ W_enc, const float* __restrict__ b_enc,
    const ushort* __restrict__ W0b, const ushort* __restrict__ Wm1b,
    const ushort* __restrict__ Wm2b, const ushort* __restrict__ Wm3b,
    const ushort* __restrict__ W011b, const ushort* __restrict__ W101b,
    const ushort* __restrict__ W111b,
    const float* __restrict__ bm1, const float* __restrict__ bm2,
    float* __restrict__ B_a, float* __restrict__ B_v)
{
    __shared__ __align__(16) ushort sY0[64 * 72];     // [e][72]: 0..31 y000, 32..63 y110
    __shared__ __align__(16) ushort sRELV[64 * 104];  // [e]: in: re*lv_i; out: psi_v
    __shared__ __align__(16) ushort sACT[64 * 136];   // [e][136] act / final psi_a
    __shared__ __align__(16) float sRS[64 * 4];       // [e]: rsx,rsy,rsz,src-id-bits

    const int t = threadIdx.x;
    const int e0 = blockIdx.x * EB;

    // ---- phase 1: per-edge features -> LDS (wave-row partitioned) ----
    {
        const int e = t >> 2;          // wave w owns e in [16w,16w+16)
        const int p = t & 3;           // 8 channels each
        const int qe = min(e0 + e, N_EDGES - 1);
        f32x4 edv = __builtin_nontemporal_load((const f32x4*)edgeS + qe);
        int sid = __builtin_nontemporal_load(srcIdS + qe);
        float rx = edv[0], ry = edv[1], rz = edv[2];
        int dn = __float_as_int(edv[3]);
        float r = sqrtf(rx * rx + ry * ry + rz * rz);

        float rad[8];
#pragma unroll
        for (int k = 0; k < 8; ++k) {
            float d = (r - (5.0f / 7.0f) * (float)k) * 1.6f;
            rad[k] = __expf(-d * d);
        }
        float n14 = 1.4f * r;
        float ex = __expf(2.f * n14);
        float th = 1.f - 2.f / (ex + 1.f);          // tanh(n14), inf-safe
        float tt = th / fmaxf(n14, 1e-6f);
        float rsx = 1.4f * rx * tt, rsy = 1.4f * ry * tt, rsz = 1.4f * rz * tt;
        if (p == 0) {
            *(float4*)&sRS[e * 4] = make_float4(rsx, rsy, rsz, __int_as_float(sid));
        }

        float la[8];
        {
            const float4* lap = (const float4*)(LN + (size_t)dn * 128 + p * 8);
            float4 A = lap[0], B = lap[1];
            la[0] = A.x; la[1] = A.y; la[2] = A.z; la[3] = A.w;
            la[4] = B.x; la[5] = B.y; la[6] = B.z; la[7] = B.w;
        }
        float lv[24];
        {
            const float4* lvp = (const float4*)(LN + (size_t)dn * 128 + 32 + p * 24);
#pragma unroll
            for (int q = 0; q < 6; ++q) {
                float4 v = lvp[q];
                lv[q * 4 + 0] = v.x; lv[q * 4 + 1] = v.y;
                lv[q * 4 + 2] = v.z; lv[q * 4 + 3] = v.w;
            }
        }

        ushort8 u000, u110, url[3];
#pragma unroll
        for (int j = 0; j < 8; ++j) {
            int c = p * 8 + j;
            const float4* we = (const float4*)(W_enc + c * 8);
            float4 w0v = we[0], w1v = we[1];
            float re = b_enc[c]
                     + rad[0] * w0v.x + rad[1] * w0v.y + rad[2] * w0v.z + rad[3] * w0v.w
                     + rad[4] * w1v.x + rad[5] * w1v.y + rad[6] * w1v.z + rad[7] * w1v.w;
            float lvx = lv[j * 3 + 0], lvy = lv[j * 3 + 1], lvz = lv[j * 3 + 2];
            float dotv = lvx * rsx + lvy * rsy + lvz * rsz;
            u000[j] = f2bf(la[j] * re);
            u110[j] = f2bf(re * dotv);
            url[0][j] = f2bf(re * lvx);
            url[1][j] = f2bf(re * lvy);
            url[2][j] = f2bf(re * lvz);
        }
        *(ushort8*)&sY0[e * 72 + p * 8]      = u000;
        *(ushort8*)&sY0[e * 72 + 32 + p * 8] = u110;
#pragma unroll
        for (int i = 0; i < 3; ++i)
            *(ushort8*)&sRELV[e * 104 + i * 32 + p * 8] = url[i];
    }

    const int lane = t & 63;
    const int w = t >> 6;
    const int r0 = lane & 15;
    const int quad = lane >> 4;
    const int colw = w * 32;               // this wave's output-channel base

    const short8* W0f   = (const short8*)W0b;
    const short8* Wm1f  = (const short8*)Wm1b;
    const short8* Wm2f  = (const short8*)Wm2b;
    const short8* Wm3f  = (const short8*)Wm3b;
    const short8* W011f = (const short8*)W011b;
    const short8* W101f = (const short8*)W101b;
    const short8* W111f = (const short8*)W111b;

    // prefetch psi0 weights: latency hidden under psi_v MFMAs
    short8 W0r[2][2];
#pragma unroll
    for (int nt2 = 0; nt2 < 2; ++nt2) {
        W0r[nt2][0] = W0f[((w * 2 + nt2) * 2 + 0) * 64 + lane];
        W0r[nt2][1] = W0f[((w * 2 + nt2) * 2 + 1) * 64 + lane];
    }

    // ---- psi_v (wave-local rows; BEFORE any barrier), swapped MFMA ----
    // thread owns edge arow = w*16+r0; outputs channels nt*16+quad*4+rr
    {
        short8 b011[2], b111[2], b101[2];
#pragma unroll
        for (int nt = 0; nt < 2; ++nt) {
            b011[nt] = W011f[nt * 64 + lane];
            b111[nt] = W111f[nt * 64 + lane];
            b101[nt] = W101f[nt * 64 + lane];
        }
        const int arow = w * 16 + r0;
        short8 aY0 = *(const short8*)&sY0[arow * 72 + quad * 8];
        short8 aRL[3];
#pragma unroll
        for (int i = 0; i < 3; ++i)
            aRL[i] = *(const short8*)&sRELV[arow * 104 + i * 32 + quad * 8];
        float4 rsv = *(const float4*)&sRS[arow * 4];

#pragma unroll
        for (int nt = 0; nt < 2; ++nt) {
            __builtin_amdgcn_s_setprio(1);
            f32x4 sA = MFMA(b011[nt], aY0, (f32x4){0.f, 0.f, 0.f, 0.f}, 0, 0, 0);
            f32x4 U[3], T[3];
#pragma unroll
            for (int i = 0; i < 3; ++i) {
                U[i] = MFMA(b111[nt], aRL[i], (f32x4){0.f, 0.f, 0.f, 0.f}, 0, 0, 0);
                T[i] = MFMA(b101[nt], aRL[i], (f32x4){0.f, 0.f, 0.f, 0.f}, 0, 0, 0);
            }
            __builtin_amdgcn_s_setprio(0);
            f32x4 ox, oy, oz;
#pragma unroll
            for (int rr = 0; rr < 4; ++rr) {
                float s = sA[rr];
                float ux = U[0][rr], uy = U[1][rr], uz = U[2][rr];
                ox[rr] = s * rsv.x + T[0][rr] + uy * rsv.z - uz * rsv.y;
                oy[rr] = s * rsv.y + T[1][rr] + uz * rsv.x - ux * rsv.z;
                oz[rr] = s * rsv.z + T[2][rr] + ux * rsv.y - uy * rsv.x;
            }
            int cb = nt * 16 + quad * 4;
            *(uint2*)&sRELV[arow * 104 + 0 * 32 + cb] = pk4(ox);
            *(uint2*)&sRELV[arow * 104 + 1 * 32 + cb] = pk4(oy);
            *(uint2*)&sRELV[arow * 104 + 2 * 32 + cb] = pk4(oz);
        }
    }

    __syncthreads();                       // B1: features + psi_v visible

    // prefetch h1 weights: latency hidden under psi0 MFMAs
    short8 Wm1r[2][4];
#pragma unroll
    for (int nt2 = 0; nt2 < 2; ++nt2)
#pragma unroll
        for (int kb = 0; kb < 4; ++kb)
            Wm1r[nt2][kb] = Wm1f[((w * 2 + nt2) * 4 + kb) * 64 + lane];

    // ---- psi0 = W0cat @ Y0^T (swapped): edge g*16+r0, chans quad*4+rr ----
    f32x4 p0[4][2];
    __builtin_amdgcn_s_setprio(1);
#pragma unroll
    for (int g = 0; g < 4; ++g) {
        short8 a0 = *(const short8*)&sY0[(g * 16 + r0) * 72 + quad * 8];
        short8 a1 = *(const short8*)&sY0[(g * 16 + r0) * 72 + 32 + quad * 8];
#pragma unroll
        for (int nt2 = 0; nt2 < 2; ++nt2) {
            f32x4 acc = {0.f, 0.f, 0.f, 0.f};
            acc = MFMA(W0r[nt2][0], a0, acc, 0, 0, 0);
            acc = MFMA(W0r[nt2][1], a1, acc, 0, 0, 0);
            p0[g][nt2] = acc;
            *(uint2*)&sACT[(g * 16 + r0) * 136 + colw + nt2 * 16 + quad * 4] =
                pk4(acc);
        }
    }
    __builtin_amdgcn_s_setprio(0);
    __syncthreads();                       // B2: psi0 activations ready

    // ---- h1 = leaky(Wm1 @ act^T + bm1), swapped ----
    f32x4 hv[2][4];
    {
        f32x4 bv0 = *(const f32x4*)&bm1[colw + 0 * 16 + quad * 4];
        f32x4 bv1 = *(const f32x4*)&bm1[colw + 1 * 16 + quad * 4];
        __builtin_amdgcn_s_setprio(1);
#pragma unroll
        for (int g = 0; g < 4; ++g) {
            short8 af[4];
#pragma unroll
            for (int kb = 0; kb < 4; ++kb)
                af[kb] = *(const short8*)&sACT[(g * 16 + r0) * 136 + kb * 32 + quad * 8];
            f32x4 aA = bv0, aB = bv1;
#pragma unroll
            for (int kb = 0; kb < 4; ++kb) {
                aA = MFMA(Wm1r[0][kb], af[kb], aA, 0, 0, 0);
                aB = MFMA(Wm1r[1][kb], af[kb], aB, 0, 0, 0);
            }
#pragma unroll
            for (int rr = 0; rr < 4; ++rr) { aA[rr] = leaky(aA[rr]); aB[rr] = leaky(aB[rr]); }
            hv[0][g] = aA; hv[1][g] = aB;
        }
        __builtin_amdgcn_s_setprio(0);
    }
    __syncthreads();                       // B3a: psi0 reads complete

    // prefetch h2 weights during h1 store region
    short8 Wm2r[2][4];
#pragma unroll
    for (int nt2 = 0; nt2 < 2; ++nt2)
#pragma unroll
        for (int kb = 0; kb < 4; ++kb)
            Wm2r[nt2][kb] = Wm2f[((w * 2 + nt2) * 4 + kb) * 64 + lane];

#pragma unroll
    for (int nt2 = 0; nt2 < 2; ++nt2)
#pragma unroll
        for (int g = 0; g < 4; ++g)
            *(uint2*)&sACT[(g * 16 + r0) * 136 + colw + nt2 * 16 + quad * 4] =
                pk4(hv[nt2][g]);
    __syncthreads();                       // B3b: h1 ready

    // ---- h2 = leaky(Wm2 @ act^T + bm2), swapped ----
    {
        f32x4 bv0 = *(const f32x4*)&bm2[colw + 0 * 16 + quad * 4];
        f32x4 bv1 = *(const f32x4*)&bm2[colw + 1 * 16 + quad * 4];
        __builtin_amdgcn_s_setprio(1);
#pragma unroll
        for (int g = 0; g < 4; ++g) {
            short8 af[4];
#pragma unroll
            for (int kb = 0; kb < 4; ++kb)
                af[kb] = *(const short8*)&sACT[(g * 16 + r0) * 136 + kb * 32 + quad * 8];
            f32x4 aA = bv0, aB = bv1;
#pragma unroll
            for (int kb = 0; kb < 4; ++kb) {
                aA = MFMA(Wm2r[0][kb], af[kb], aA, 0, 0, 0);
                aB = MFMA(Wm2r[1][kb], af[kb], aB, 0, 0, 0);
            }
#pragma unroll
            for (int rr = 0; rr < 4; ++rr) { aA[rr] = leaky(aA[rr]); aB[rr] = leaky(aB[rr]); }
            hv[0][g] = aA; hv[1][g] = aB;
        }
        __builtin_amdgcn_s_setprio(0);
    }
    __syncthreads();                       // B4a: h1 reads complete

    // prefetch psi_a weights during h2 store region
    short8 Wm3r[2][4];
#pragma unroll
    for (int nt2 = 0; nt2 < 2; ++nt2)
#pragma unroll
        for (int kb = 0; kb < 4; ++kb)
            Wm3r[nt2][kb] = Wm3f[((w * 2 + nt2) * 4 + kb) * 64 + lane];

#pragma unroll
    for (int nt2 = 0; nt2 < 2; ++nt2)
#pragma unroll
        for (int g = 0; g < 4; ++g)
            *(uint2*)&sACT[(g * 16 + r0) * 136 + colw + nt2 * 16 + quad * 4] =
                pk4(hv[nt2][g]);
    __syncthreads();                       // B4b: h2 ready

    // ---- psi_a = psi0 + Wm3 @ h2^T, swapped ----
    f32x4 fv[2][4];
    __builtin_amdgcn_s_setprio(1);
#pragma unroll
    for (int g = 0; g < 4; ++g) {
        short8 af[4];
#pragma unroll
        for (int kb = 0; kb < 4; ++kb)
            af[kb] = *(const short8*)&sACT[(g * 16 + r0) * 136 + kb * 32 + quad * 8];
#pragma unroll
        for (int nt2 = 0; nt2 < 2; ++nt2) {
            f32x4 acc = {0.f, 0.f, 0.f, 0.f};
#pragma unroll
            for (int kb = 0; kb < 4; ++kb)
                acc = MFMA(Wm3r[nt2][kb], af[kb], acc, 0, 0, 0);
#pragma unroll
            for (int rr = 0; rr < 4; ++rr) acc[rr] += p0[g][nt2][rr];
            fv[nt2][g] = acc;
        }
    }
    __builtin_amdgcn_s_setprio(0);
    __syncthreads();                       // B5a: all h2 reads complete
#pragma unroll
    for (int nt2 = 0; nt2 < 2; ++nt2)
#pragma unroll
        for (int g = 0; g < 4; ++g)
            *(uint2*)&sACT[(g * 16 + r0) * 136 + colw + nt2 * 16 + quad * 4] =
                pk4(fv[nt2][g]);
    __syncthreads();                       // B5b: psi_a (sACT) + psi_v (sRELV)

    // ---- fused segmented reduction over the block's src-sorted edges ----
    // thread t<128: psi_a col t; t in [128,224): psi_v col t-128 (= i*32+d).
    // interior runs -> NT store; runs touching block edge -> atomicAdd.
    {
        const int nE = min(EB, N_EDGES - e0);
        if (t < 224) {
            const bool isA = (t < 128);
            const int j = isA ? t : t - 128;
            const int dcol = j & 31, icol = j >> 5;
            float acc = 0.f;
            int cur = __float_as_int(sRS[3]);   // src id of edge 0
            int runstart = 0;
            for (int el = 0; el < nE; ++el) {
                int s = __float_as_int(sRS[el * 4 + 3]);
                if (s != cur) {
                    float v = 0.1f * acc;
                    float* p = isA ? (B_a + (size_t)cur * 128 + j)
                                   : (B_v + (size_t)cur * 96 + dcol * 3 + icol);
                    if (runstart == 0) atomicAdd(p, v);
                    else __builtin_nontemporal_store(v, p);
                    acc = 0.f; cur = s; runstart = el;
                }
                acc += isA ? bf2f(sACT[el * 136 + j])
                           : bf2f(sRELV[el * 104 + j]);
            }
            float v = 0.1f * acc;              // last run: always boundary
            if (isA) atomicAdd(B_a + (size_t)cur * 128 + j, v);
            else     atomicAdd(B_v + (size_t)cur * 96 + dcol * 3 + icol, v);
        }
    }
}

extern "C" void kernel_launch(void* const* d_in, const int* in_sizes, int n_in,
                              void* d_out, int out_size, void* d_ws, size_t ws_size,
                              hipStream_t stream) {
    const float* x_a   = (const float*)d_in[0];
    const float* x_v   = (const float*)d_in[1];
    const float* r_ij  = (const float*)d_in[2];
    const int*   src   = (const int*)d_in[3];
    const int*   dst   = (const int*)d_in[4];
    const float* W_L0  = (const float*)d_in[5];
    const float* W_L1  = (const float*)d_in[6];
    const float* W_enc = (const float*)d_in[7];
    const float* b_enc = (const float*)d_in[8];
    const float* Wy000 = (const float*)d_in[9];
    const float* Wy110 = (const float*)d_in[10];
    const float* Wy011 = (const float*)d_in[11];
    const float* Wy101 = (const float*)d_in[12];
    const float* Wy111 = (const float*)d_in[13];
    const float* Wm1   = (const float*)d_in[14];
    const float* bm1   = (const float*)d_in[15];
    const float* Wm2   = (const float*)d_in[16];
    const float* bm2   = (const float*)d_in[17];
    const float* Wm3   = (const float*)d_in[18];

    float* out = (float*)d_out;
    float* B_a = out;
    float* B_v = out + (size_t)N_NODES * DIM_A;

    char* w = (char*)d_ws;
    float* LN     = (float*)w;  w += (size_t)N_NODES * 128 * 4;   // 25.6 MB
    int*   degS   = (int*)w;    w += (size_t)N_NODES * 4;
    int*   curS   = (int*)w;    w += (size_t)N_NODES * 4;
    int*   excl   = (int*)w;    w += (size_t)N_NODES * 4;
    int*   bsum   = (int*)w;    w += 64 * 4;
    int*   srcIdS = (int*)w;    w += (size_t)N_EDGES * 4;
    float4* edgeS = (float4*)w; w += (size_t)N_EDGES * 16;
    ushort* W0b   = (ushort*)w; w += 128 * 64 * 2;
    ushort* Wm1b  = (ushort*)w; w += 128 * 128 * 2;
    ushort* Wm2b  = (ushort*)w; w += 128 * 128 * 2;
    ushort* Wm3b  = (ushort*)w; w += 128 * 128 * 2;
    ushort* W011b = (ushort*)w; w += 32 * 32 * 2;
    ushort* W101b = (ushort*)w; w += 32 * 32 * 2;
    ushort* W111b = (ushort*)w; w += 32 * 32 * 2;

    (void)hipMemsetAsync(degS, 0, N_NODES * sizeof(int), stream);

    prep_kernel<<<(N_NODES + 7) / 8, 256, 0, stream>>>(
        x_a, x_v, W_L0, W_L1, src,
        Wy000, Wy110, Wy011, Wy101, Wy111, Wm1, Wm2, Wm3,
        LN, degS, W0b, Wm1b, Wm2b, Wm3b, W011b, W101b, W111b);

    scan1_kernel<<<SCAN_B, 1024, 0, stream>>>(degS, excl, bsum);
    scan3_kernel<<<SCAN_B, 1024, 0, stream>>>(excl, bsum, curS,
                                              (f32x4*)d_out,
                                              (N_NODES * 224) / 4);

    scatter_kernel<<<(N_EDGES + 255) / 256, 256, 0, stream>>>(src, dst, r_ij, curS,
                                                              edgeS, srcIdS);

    edge_mfma_kernel<<<(N_EDGES + EB - 1) / EB, 256, 0, stream>>>(
        edgeS, srcIdS, LN, W_enc, b_enc,
        W0b, Wm1b, Wm2b, Wm3b, W011b, W101b, W111b,
        bm1, bm2, B_a, B_v);
}

// Round 9
// 353.944 us; speedup vs baseline: 1.3359x; 1.3359x over previous
//
#include <hip/hip_runtime.h>
#include <hip/hip_bf16.h>

#define N_NODES 50000
#define N_EDGES 500000
#define DIM_A 128
#define DIM_V 32
#define CHAN 32
#define EB 64            // edges per block in edge kernel
#define SCAN_B 49        // ceil(50000/1024)

typedef __attribute__((ext_vector_type(8))) short short8;
typedef __attribute__((ext_vector_type(8))) unsigned short ushort8;
typedef __attribute__((ext_vector_type(4))) float f32x4;
typedef unsigned short ushort;

#define MFMA __builtin_amdgcn_mfma_f32_16x16x32_bf16

__device__ __forceinline__ ushort f2bf(float x) {
    __hip_bfloat16 h = __float2bfloat16(x);
    return *reinterpret_cast<ushort*>(&h);
}
__device__ __forceinline__ float bf2f(ushort u) {
    union { float f; unsigned int i; } v; v.i = ((unsigned int)u) << 16; return v.f;
}
__device__ __forceinline__ float leaky(float x) {
    return x >= 0.f ? x : 0.1f * x;
}
// pack 4 f32 -> 4 bf16 (2 dwords), bit-exact vs scalar f2bf path.
__device__ __forceinline__ uint2 pk4(f32x4 v) {
    uint2 r;
    r.x = (unsigned)f2bf(v[0]) | ((unsigned)f2bf(v[1]) << 16);
    r.y = (unsigned)f2bf(v[2]) | ((unsigned)f2bf(v[3]) << 16);
    return r;
}

// ---------------- fused prep: convw + node_proj (LDS-staged) + hist ---------
// v7: node_proj was HBM-latency-serialized (32 lanes re-reading the same row
// -> 32B useful/VMEM instr; VGPR=48 -> ~2 loads in flight; 168us at 8% VALU).
// Fix: stage x_a/x_v/W_L0/W_L1 into LDS with coalesced full-wave loads, then
// compute dots from LDS (x reads broadcast; sW0 stride 132 & sW1 stride 36
// keep column access to <=4-way conflicts). Same math, same output layout.
__global__ __launch_bounds__(256) void prep_kernel(
    const float* __restrict__ x_a, const float* __restrict__ x_v,
    const float* __restrict__ W_L0, const float* __restrict__ W_L1,
    const int* __restrict__ src,
    const float* __restrict__ Wy000, const float* __restrict__ Wy110,
    const float* __restrict__ Wy011, const float* __restrict__ Wy101,
    const float* __restrict__ Wy111,
    const float* __restrict__ Wm1, const float* __restrict__ Wm2,
    const float* __restrict__ Wm3,
    float* __restrict__ LN, int* __restrict__ degS,
    ushort* __restrict__ W0b, ushort* __restrict__ Wm1b,
    ushort* __restrict__ Wm2b, ushort* __restrict__ Wm3b,
    ushort* __restrict__ W011b, ushort* __restrict__ W101b,
    ushort* __restrict__ W111b)
{
    __shared__ __align__(16) float sX[8 * 128];    // x_a rows      (4 KB)
    __shared__ __align__(16) float sV[8 * 96];     // x_v rows      (3 KB)
    __shared__ __align__(16) float sW0[32 * 132];  // W_L0, padded  (16.9 KB)
    __shared__ __align__(16) float sW1[32 * 36];   // W_L1, padded  (4.6 KB)

    const int t = threadIdx.x;
    const int g = blockIdx.x * 256 + t;
    const int n0 = blockIdx.x * 8;

    // --- stage x_a: 8 rows x 128 floats = 256 float4, 1/thread ---
    {
        int nl = t >> 5, k4 = t & 31;
        *(float4*)&sX[nl * 128 + k4 * 4] =
            *(const float4*)(x_a + (size_t)(n0 + nl) * DIM_A + k4 * 4);
    }
    // --- stage x_v: 8 rows x 96 floats = 192 float4 ---
    if (t < 192) {
        int nl = t / 24, j = t - nl * 24;
        *(float4*)&sV[nl * 96 + j * 4] =
            *(const float4*)(x_v + (size_t)(n0 + nl) * 96 + j * 4);
    }
    // --- stage W_L0: 32x128 = 1024 float4, 4/thread ---
#pragma unroll
    for (int i = 0; i < 4; ++i) {
        int idx = i * 256 + t;
        int row = idx >> 5, k4 = idx & 31;
        *(float4*)&sW0[row * 132 + k4 * 4] =
            *(const float4*)(W_L0 + row * DIM_A + k4 * 4);
    }
    // --- stage W_L1: 32x32 = 256 float4, 1/thread ---
    {
        int row = t >> 3, j = t & 7;
        *(float4*)&sW1[row * 36 + j * 4] =
            *(const float4*)(W_L1 + row * DIM_V + j * 4);
    }

    // --- histogram (independent; overlaps staging latency) ---
    if (g < N_EDGES) atomicAdd(&degS[src[g]], 1);

    // --- weight conversion (blocks 0..63) ---
    if (g < 128 * 128) {          // [128][128] matrices, KB=4
        int o = g >> 7, c = g & 127;
        int pi = ((o >> 4) * 4 + (c >> 5)) * 512 + ((c >> 3) & 3) * 128
               + (o & 15) * 8 + (c & 7);
        Wm1b[pi] = f2bf(Wm1[g]);
        Wm2b[pi] = f2bf(Wm2[g]);
        Wm3b[pi] = f2bf(Wm3[g]);
    }
    if (g < 128 * 64) {           // W0cat [128][64], KB=2; c<32 Wy000 else Wy110
        int o = g >> 6, c = g & 63;
        float v = (c < 32) ? Wy000[o * 32 + c] : Wy110[o * 32 + (c - 32)];
        int pi = ((o >> 4) * 2 + (c >> 5)) * 512 + ((c >> 3) & 3) * 128
               + (o & 15) * 8 + (c & 7);
        W0b[pi] = f2bf(v);
    }
    if (g < 32 * 32) {            // [32][32] matrices, KB=1
        int o = g >> 5, c = g & 31;
        int pi = (o >> 4) * 512 + ((c >> 3) & 3) * 128 + (o & 15) * 8 + (c & 7);
        W011b[pi] = f2bf(Wy011[g]);
        W101b[pi] = f2bf(Wy101[g]);
        W111b[pi] = f2bf(Wy111[g]);
    }

    __syncthreads();

    // --- node projection from LDS: LN[n][128] = [L0(32) | L1(96, c*3+i)] ---
    const int n = t >> 5;
    const int c = t & 31;

    float acc = 0.f;
#pragma unroll 8
    for (int k = 0; k < DIM_A / 4; ++k) {
        float4 x = *(const float4*)&sX[n * 128 + k * 4];
        float4 w = *(const float4*)&sW0[c * 132 + k * 4];
        acc += x.x * w.x + x.y * w.y + x.z * w.z + x.w * w.w;
    }
    LN[(size_t)(n0 + n) * 128 + c] = acc;

    float a0 = 0.f, a1 = 0.f, a2 = 0.f;
#pragma unroll
    for (int dd = 0; dd < DIM_V / 4; ++dd) {
        float4 wv = *(const float4*)&sW1[c * 36 + dd * 4];
        float4 f0 = *(const float4*)&sV[n * 96 + dd * 12 + 0];
        float4 f1 = *(const float4*)&sV[n * 96 + dd * 12 + 4];
        float4 f2 = *(const float4*)&sV[n * 96 + dd * 12 + 8];
        a0 += wv.x * f0.x + wv.y * f0.w + wv.z * f1.z + wv.w * f2.y;
        a1 += wv.x * f0.y + wv.y * f1.x + wv.z * f1.w + wv.w * f2.z;
        a2 += wv.x * f0.z + wv.y * f1.y + wv.z * f2.x + wv.w * f2.w;
    }
    float* o = LN + (size_t)(n0 + n) * 128 + 32 + c * 3;
    o[0] = a0; o[1] = a1; o[2] = a2;
}

// ---------------- scan phase 1: per-1024-block inclusive scan ---------------
__global__ __launch_bounds__(1024) void scan1_kernel(const int* __restrict__ deg,
                                                     int* __restrict__ excl,
                                                     int* __restrict__ bsum)
{
    __shared__ int buf[1024];
    int t = threadIdx.x;
    int i = blockIdx.x * 1024 + t;
    int v = (i < N_NODES) ? deg[i] : 0;
    buf[t] = v;
    __syncthreads();
    for (int off = 1; off < 1024; off <<= 1) {
        int x = (t >= off) ? buf[t - off] : 0;
        __syncthreads();
        buf[t] += x;
        __syncthreads();
    }
    if (i < N_NODES) excl[i] = buf[t] - v;
    if (t == 1023) bsum[blockIdx.x] = buf[1023];
}

// ---------------- scan phase 2: add bsum prefix -> cursor; zero d_out -------
__global__ __launch_bounds__(1024) void scan3_kernel(const int* __restrict__ excl,
                                                     const int* __restrict__ bsum,
                                                     int* __restrict__ cursor,
                                                     f32x4* __restrict__ out4,
                                                     int total4)
{
    __shared__ int sOff;
    int t = threadIdx.x;
    if (t == 0) {
        int s = 0;
#pragma unroll
        for (int k = 0; k < SCAN_B; ++k)
            s += (k < blockIdx.x) ? bsum[k] : 0;
        sOff = s;
    }
    // zero output while the prefix load resolves
    f32x4 z = {0.f, 0.f, 0.f, 0.f};
    for (int i = blockIdx.x * 1024 + t; i < total4; i += SCAN_B * 1024)
        __builtin_nontemporal_store(z, out4 + i);
    __syncthreads();
    int i = blockIdx.x * 1024 + t;
    if (i < N_NODES) cursor[i] = excl[i] + sOff;
}

// ---------------- scatter: build src-sorted packed edge records -------------
__global__ __launch_bounds__(256) void scatter_kernel(
    const int* __restrict__ src, const int* __restrict__ dst,
    const float* __restrict__ r_ij, int* __restrict__ curS,
    float4* __restrict__ edgeS, int* __restrict__ srcIdS)
{
    int i = blockIdx.x * 256 + threadIdx.x;
    if (i < N_EDGES) {
        int s = src[i];
        int p = atomicAdd(&curS[s], 1);
        edgeS[p] = make_float4(r_ij[i * 3 + 0], r_ij[i * 3 + 1], r_ij[i * 3 + 2],
                               __int_as_float(dst[i]));
        srcIdS[p] = s;
    }
}

// ---------------- MFMA edge kernel, fused segmented reduction ---------------
// v6b: operand-swapped MFMAs (W @ act^T) -> thread holds 4 consecutive
// channels of ONE edge; store phases use packed ds_write_b64 (pk4 = bit-exact
// f2bf packing). LDS exactly 40960 B.
__global__ __launch_bounds__(256, 4) void edge_mfma_kernel(
    const float4* __restrict__ edgeS, const int* __restrict__ srcIdS,
    const float* __restrict__ LN,
    const float* __restrict__ W_enc, const float* __restrict__ b_enc,
    const ushort* __restrict__ W0b, const ushort* __restrict__ Wm1b,
    const ushort* __restrict__ Wm2b, const ushort* __restrict__ Wm3b,
    const ushort* __restrict__ W011b, const ushort* __restrict__ W101b,
    const ushort* __restrict__ W111b,
    const float* __restrict__ bm1, const float* __restrict__ bm2,
    float* __restrict__ B_a, float* __restrict__ B_v)
{
    __shared__ __align__(16) ushort sY0[64 * 72];     // [e][72]: 0..31 y000, 32..63 y110
    __shared__ __align__(16) ushort sRELV[64 * 104];  // [e]: in: re*lv_i; out: psi_v
    __shared__ __align__(16) ushort sACT[64 * 136];   // [e][136] act / final psi_a
    __shared__ __align__(16) float sRS[64 * 4];       // [e]: rsx,rsy,rsz,src-id-bits

    const int t = threadIdx.x;
    const int e0 = blockIdx.x * EB;

    // ---- phase 1: per-edge features -> LDS (wave-row partitioned) ----
    {
        const int e = t >> 2;          // wave w owns e in [16w,16w+16)
        const int p = t & 3;           // 8 channels each
        const int qe = min(e0 + e, N_EDGES - 1);
        f32x4 edv = __builtin_nontemporal_load((const f32x4*)edgeS + qe);
        int sid = __builtin_nontemporal_load(srcIdS + qe);
        float rx = edv[0], ry = edv[1], rz = edv[2];
        int dn = __float_as_int(edv[3]);
        float r = sqrtf(rx * rx + ry * ry + rz * rz);

        float rad[8];
#pragma unroll
        for (int k = 0; k < 8; ++k) {
            float d = (r - (5.0f / 7.0f) * (float)k) * 1.6f;
            rad[k] = __expf(-d * d);
        }
        float n14 = 1.4f * r;
        float ex = __expf(2.f * n14);
        float th = 1.f - 2.f / (ex + 1.f);          // tanh(n14), inf-safe
        float tt = th / fmaxf(n14, 1e-6f);
        float rsx = 1.4f * rx * tt, rsy = 1.4f * ry * tt, rsz = 1.4f * rz * tt;
        if (p == 0) {
            *(float4*)&sRS[e * 4] = make_float4(rsx, rsy, rsz, __int_as_float(sid));
        }

        float la[8];
        {
            const float4* lap = (const float4*)(LN + (size_t)dn * 128 + p * 8);
            float4 A = lap[0], B = lap[1];
            la[0] = A.x; la[1] = A.y; la[2] = A.z; la[3] = A.w;
            la[4] = B.x; la[5] = B.y; la[6] = B.z; la[7] = B.w;
        }
        float lv[24];
        {
            const float4* lvp = (const float4*)(LN + (size_t)dn * 128 + 32 + p * 24);
#pragma unroll
            for (int q = 0; q < 6; ++q) {
                float4 v = lvp[q];
                lv[q * 4 + 0] = v.x; lv[q * 4 + 1] = v.y;
                lv[q * 4 + 2] = v.z; lv[q * 4 + 3] = v.w;
            }
        }

        ushort8 u000, u110, url[3];
#pragma unroll
        for (int j = 0; j < 8; ++j) {
            int c = p * 8 + j;
            const float4* we = (const float4*)(W_enc + c * 8);
            float4 w0v = we[0], w1v = we[1];
            float re = b_enc[c]
                     + rad[0] * w0v.x + rad[1] * w0v.y + rad[2] * w0v.z + rad[3] * w0v.w
                     + rad[4] * w1v.x + rad[5] * w1v.y + rad[6] * w1v.z + rad[7] * w1v.w;
            float lvx = lv[j * 3 + 0], lvy = lv[j * 3 + 1], lvz = lv[j * 3 + 2];
            float dotv = lvx * rsx + lvy * rsy + lvz * rsz;
            u000[j] = f2bf(la[j] * re);
            u110[j] = f2bf(re * dotv);
            url[0][j] = f2bf(re * lvx);
            url[1][j] = f2bf(re * lvy);
            url[2][j] = f2bf(re * lvz);
        }
        *(ushort8*)&sY0[e * 72 + p * 8]      = u000;
        *(ushort8*)&sY0[e * 72 + 32 + p * 8] = u110;
#pragma unroll
        for (int i = 0; i < 3; ++i)
            *(ushort8*)&sRELV[e * 104 + i * 32 + p * 8] = url[i];
    }

    const int lane = t & 63;
    const int w = t >> 6;
    const int r0 = lane & 15;
    const int quad = lane >> 4;
    const int colw = w * 32;               // this wave's output-channel base

    const short8* W0f   = (const short8*)W0b;
    const short8* Wm1f  = (const short8*)Wm1b;
    const short8* Wm2f  = (const short8*)Wm2b;
    const short8* Wm3f  = (const short8*)Wm3b;
    const short8* W011f = (const short8*)W011b;
    const short8* W101f = (const short8*)W101b;
    const short8* W111f = (const short8*)W111b;

    // prefetch psi0 weights: latency hidden under psi_v MFMAs
    short8 W0r[2][2];
#pragma unroll
    for (int nt2 = 0; nt2 < 2; ++nt2) {
        W0r[nt2][0] = W0f[((w * 2 + nt2) * 2 + 0) * 64 + lane];
        W0r[nt2][1] = W0f[((w * 2 + nt2) * 2 + 1) * 64 + lane];
    }

    // ---- psi_v (wave-local rows; BEFORE any barrier), swapped MFMA ----
    {
        short8 b011[2], b111[2], b101[2];
#pragma unroll
        for (int nt = 0; nt < 2; ++nt) {
            b011[nt] = W011f[nt * 64 + lane];
            b111[nt] = W111f[nt * 64 + lane];
            b101[nt] = W101f[nt * 64 + lane];
        }
        const int arow = w * 16 + r0;
        short8 aY0 = *(const short8*)&sY0[arow * 72 + quad * 8];
        short8 aRL[3];
#pragma unroll
        for (int i = 0; i < 3; ++i)
            aRL[i] = *(const short8*)&sRELV[arow * 104 + i * 32 + quad * 8];
        float4 rsv = *(const float4*)&sRS[arow * 4];

#pragma unroll
        for (int nt = 0; nt < 2; ++nt) {
            __builtin_amdgcn_s_setprio(1);
            f32x4 sA = MFMA(b011[nt], aY0, (f32x4){0.f, 0.f, 0.f, 0.f}, 0, 0, 0);
            f32x4 U[3], T[3];
#pragma unroll
            for (int i = 0; i < 3; ++i) {
                U[i] = MFMA(b111[nt], aRL[i], (f32x4){0.f, 0.f, 0.f, 0.f}, 0, 0, 0);
                T[i] = MFMA(b101[nt], aRL[i], (f32x4){0.f, 0.f, 0.f, 0.f}, 0, 0, 0);
            }
            __builtin_amdgcn_s_setprio(0);
            f32x4 ox, oy, oz;
#pragma unroll
            for (int rr = 0; rr < 4; ++rr) {
                float s = sA[rr];
                float ux = U[0][rr], uy = U[1][rr], uz = U[2][rr];
                ox[rr] = s * rsv.x + T[0][rr] + uy * rsv.z - uz * rsv.y;
                oy[rr] = s * rsv.y + T[1][rr] + uz * rsv.x - ux * rsv.z;
                oz[rr] = s * rsv.z + T[2][rr] + ux * rsv.y - uy * rsv.x;
            }
            int cb = nt * 16 + quad * 4;
            *(uint2*)&sRELV[arow * 104 + 0 * 32 + cb] = pk4(ox);
            *(uint2*)&sRELV[arow * 104 + 1 * 32 + cb] = pk4(oy);
            *(uint2*)&sRELV[arow * 104 + 2 * 32 + cb] = pk4(oz);
        }
    }

    __syncthreads();                       // B1: features + psi_v visible

    // prefetch h1 weights: latency hidden under psi0 MFMAs
    short8 Wm1r[2][4];
#pragma unroll
    for (int nt2 = 0; nt2 < 2; ++nt2)
#pragma unroll
        for (int kb = 0; kb < 4; ++kb)
            Wm1r[nt2][kb] = Wm1f[((w * 2 + nt2) * 4 + kb) * 64 + lane];

    // ---- psi0 = W0cat @ Y0^T (swapped): edge g*16+r0, chans quad*4+rr ----
    f32x4 p0[4][2];
    __builtin_amdgcn_s_setprio(1);
#pragma unroll
    for (int g = 0; g < 4; ++g) {
        short8 a0 = *(const short8*)&sY0[(g * 16 + r0) * 72 + quad * 8];
        short8 a1 = *(const short8*)&sY0[(g * 16 + r0) * 72 + 32 + quad * 8];
#pragma unroll
        for (int nt2 = 0; nt2 < 2; ++nt2) {
            f32x4 acc = {0.f, 0.f, 0.f, 0.f};
            acc = MFMA(W0r[nt2][0], a0, acc, 0, 0, 0);
            acc = MFMA(W0r[nt2][1], a1, acc, 0, 0, 0);
            p0[g][nt2] = acc;
            *(uint2*)&sACT[(g * 16 + r0) * 136 + colw + nt2 * 16 + quad * 4] =
                pk4(acc);
        }
    }
    __builtin_amdgcn_s_setprio(0);
    __syncthreads();                       // B2: psi0 activations ready

    // ---- h1 = leaky(Wm1 @ act^T + bm1), swapped ----
    f32x4 hv[2][4];
    {
        f32x4 bv0 = *(const f32x4*)&bm1[colw + 0 * 16 + quad * 4];
        f32x4 bv1 = *(const f32x4*)&bm1[colw + 1 * 16 + quad * 4];
        __builtin_amdgcn_s_setprio(1);
#pragma unroll
        for (int g = 0; g < 4; ++g) {
            short8 af[4];
#pragma unroll
            for (int kb = 0; kb < 4; ++kb)
                af[kb] = *(const short8*)&sACT[(g * 16 + r0) * 136 + kb * 32 + quad * 8];
            f32x4 aA = bv0, aB = bv1;
#pragma unroll
            for (int kb = 0; kb < 4; ++kb) {
                aA = MFMA(Wm1r[0][kb], af[kb], aA, 0, 0, 0);
                aB = MFMA(Wm1r[1][kb], af[kb], aB, 0, 0, 0);
            }
#pragma unroll
            for (int rr = 0; rr < 4; ++rr) { aA[rr] = leaky(aA[rr]); aB[rr] = leaky(aB[rr]); }
            hv[0][g] = aA; hv[1][g] = aB;
        }
        __builtin_amdgcn_s_setprio(0);
    }
    __syncthreads();                       // B3a: psi0 reads complete

    // prefetch h2 weights during h1 store region
    short8 Wm2r[2][4];
#pragma unroll
    for (int nt2 = 0; nt2 < 2; ++nt2)
#pragma unroll
        for (int kb = 0; kb < 4; ++kb)
            Wm2r[nt2][kb] = Wm2f[((w * 2 + nt2) * 4 + kb) * 64 + lane];

#pragma unroll
    for (int nt2 = 0; nt2 < 2; ++nt2)
#pragma unroll
        for (int g = 0; g < 4; ++g)
            *(uint2*)&sACT[(g * 16 + r0) * 136 + colw + nt2 * 16 + quad * 4] =
                pk4(hv[nt2][g]);
    __syncthreads();                       // B3b: h1 ready

    // ---- h2 = leaky(Wm2 @ act^T + bm2), swapped ----
    {
        f32x4 bv0 = *(const f32x4*)&bm2[colw + 0 * 16 + quad * 4];
        f32x4 bv1 = *(const f32x4*)&bm2[colw + 1 * 16 + quad * 4];
        __builtin_amdgcn_s_setprio(1);
#pragma unroll
        for (int g = 0; g < 4; ++g) {
            short8 af[4];
#pragma unroll
            for (int kb = 0; kb < 4; ++kb)
                af[kb] = *(const short8*)&sACT[(g * 16 + r0) * 136 + kb * 32 + quad * 8];
            f32x4 aA = bv0, aB = bv1;
#pragma unroll
            for (int kb = 0; kb < 4; ++kb) {
                aA = MFMA(Wm2r[0][kb], af[kb], aA, 0, 0, 0);
                aB = MFMA(Wm2r[1][kb], af[kb], aB, 0, 0, 0);
            }
#pragma unroll
            for (int rr = 0; rr < 4; ++rr) { aA[rr] = leaky(aA[rr]); aB[rr] = leaky(aB[rr]); }
            hv[0][g] = aA; hv[1][g] = aB;
        }
        __builtin_amdgcn_s_setprio(0);
    }
    __syncthreads();                       // B4a: h1 reads complete

    // prefetch psi_a weights during h2 store region
    short8 Wm3r[2][4];
#pragma unroll
    for (int nt2 = 0; nt2 < 2; ++nt2)
#pragma unroll
        for (int kb = 0; kb < 4; ++kb)
            Wm3r[nt2][kb] = Wm3f[((w * 2 + nt2) * 4 + kb) * 64 + lane];

#pragma unroll
    for (int nt2 = 0; nt2 < 2; ++nt2)
#pragma unroll
        for (int g = 0; g < 4; ++g)
            *(uint2*)&sACT[(g * 16 + r0) * 136 + colw + nt2 * 16 + quad * 4] =
                pk4(hv[nt2][g]);
    __syncthreads();                       // B4b: h2 ready

    // ---- psi_a = psi0 + Wm3 @ h2^T, swapped ----
    f32x4 fv[2][4];
    __builtin_amdgcn_s_setprio(1);
#pragma unroll
    for (int g = 0; g < 4; ++g) {
        short8 af[4];
#pragma unroll
        for (int kb = 0; kb < 4; ++kb)
            af[kb] = *(const short8*)&sACT[(g * 16 + r0) * 136 + kb * 32 + quad * 8];
#pragma unroll
        for (int nt2 = 0; nt2 < 2; ++nt2) {
            f32x4 acc = {0.f, 0.f, 0.f, 0.f};
#pragma unroll
            for (int kb = 0; kb < 4; ++kb)
                acc = MFMA(Wm3r[nt2][kb], af[kb], acc, 0, 0, 0);
#pragma unroll
            for (int rr = 0; rr < 4; ++rr) acc[rr] += p0[g][nt2][rr];
            fv[nt2][g] = acc;
        }
    }
    __builtin_amdgcn_s_setprio(0);
    __syncthreads();                       // B5a: all h2 reads complete
#pragma unroll
    for (int nt2 = 0; nt2 < 2; ++nt2)
#pragma unroll
        for (int g = 0; g < 4; ++g)
            *(uint2*)&sACT[(g * 16 + r0) * 136 + colw + nt2 * 16 + quad * 4] =
                pk4(fv[nt2][g]);
    __syncthreads();                       // B5b: psi_a (sACT) + psi_v (sRELV)

    // ---- fused segmented reduction over the block's src-sorted edges ----
    {
        const int nE = min(EB, N_EDGES - e0);
        if (t < 224) {
            const bool isA = (t < 128);
            const int j = isA ? t : t - 128;
            const int dcol = j & 31, icol = j >> 5;
            float acc = 0.f;
            int cur = __float_as_int(sRS[3]);   // src id of edge 0
            int runstart = 0;
            for (int el = 0; el < nE; ++el) {
                int s = __float_as_int(sRS[el * 4 + 3]);
                if (s != cur) {
                    float v = 0.1f * acc;
                    float* p = isA ? (B_a + (size_t)cur * 128 + j)
                                   : (B_v + (size_t)cur * 96 + dcol * 3 + icol);
                    if (runstart == 0) atomicAdd(p, v);
                    else __builtin_nontemporal_store(v, p);
                    acc = 0.f; cur = s; runstart = el;
                }
                acc += isA ? bf2f(sACT[el * 136 + j])
                           : bf2f(sRELV[el * 104 + j]);
            }
            float v = 0.1f * acc;              // last run: always boundary
            if (isA) atomicAdd(B_a + (size_t)cur * 128 + j, v);
            else     atomicAdd(B_v + (size_t)cur * 96 + dcol * 3 + icol, v);
        }
    }
}

extern "C" void kernel_launch(void* const* d_in, const int* in_sizes, int n_in,
                              void* d_out, int out_size, void* d_ws, size_t ws_size,
                              hipStream_t stream) {
    const float* x_a   = (const float*)d_in[0];
    const float* x_v   = (const float*)d_in[1];
    const float* r_ij  = (const float*)d_in[2];
    const int*   src   = (const int*)d_in[3];
    const int*   dst   = (const int*)d_in[4];
    const float* W_L0  = (const float*)d_in[5];
    const float* W_L1  = (const float*)d_in[6];
    const float* W_enc = (const float*)d_in[7];
    const float* b_enc = (const float*)d_in[8];
    const float* Wy000 = (const float*)d_in[9];
    const float* Wy110 = (const float*)d_in[10];
    const float* Wy011 = (const float*)d_in[11];
    const float* Wy101 = (const float*)d_in[12];
    const float* Wy111 = (const float*)d_in[13];
    const float* Wm1   = (const float*)d_in[14];
    const float* bm1   = (const float*)d_in[15];
    const float* Wm2   = (const float*)d_in[16];
    const float* bm2   = (const float*)d_in[17];
    const float* Wm3   = (const float*)d_in[18];

    float* out = (float*)d_out;
    float* B_a = out;
    float* B_v = out + (size_t)N_NODES * DIM_A;

    char* w = (char*)d_ws;
    float* LN     = (float*)w;  w += (size_t)N_NODES * 128 * 4;   // 25.6 MB
    int*   degS   = (int*)w;    w += (size_t)N_NODES * 4;
    int*   curS   = (int*)w;    w += (size_t)N_NODES * 4;
    int*   excl   = (int*)w;    w += (size_t)N_NODES * 4;
    int*   bsum   = (int*)w;    w += 64 * 4;
    int*   srcIdS = (int*)w;    w += (size_t)N_EDGES * 4;
    float4* edgeS = (float4*)w; w += (size_t)N_EDGES * 16;
    ushort* W0b   = (ushort*)w; w += 128 * 64 * 2;
    ushort* Wm1b  = (ushort*)w; w += 128 * 128 * 2;
    ushort* Wm2b  = (ushort*)w; w += 128 * 128 * 2;
    ushort* Wm3b  = (ushort*)w; w += 128 * 128 * 2;
    ushort* W011b = (ushort*)w; w += 32 * 32 * 2;
    ushort* W101b = (ushort*)w; w += 32 * 32 * 2;
    ushort* W111b = (ushort*)w; w += 32 * 32 * 2;

    (void)hipMemsetAsync(degS, 0, N_NODES * sizeof(int), stream);

    prep_kernel<<<(N_NODES + 7) / 8, 256, 0, stream>>>(
        x_a, x_v, W_L0, W_L1, src,
        Wy000, Wy110, Wy011, Wy101, Wy111, Wm1, Wm2, Wm3,
        LN, degS, W0b, Wm1b, Wm2b, Wm3b, W011b, W101b, W111b);

    scan1_kernel<<<SCAN_B, 1024, 0, stream>>>(degS, excl, bsum);
    scan3_kernel<<<SCAN_B, 1024, 0, stream>>>(excl, bsum, curS,
                                              (f32x4*)d_out,
                                              (N_NODES * 224) / 4);

    scatter_kernel<<<(N_EDGES + 255) / 256, 256, 0, stream>>>(src, dst, r_ij, curS,
                                                              edgeS, srcIdS);

    edge_mfma_kernel<<<(N_EDGES + EB - 1) / EB, 256, 0, stream>>>(
        edgeS, srcIdS, LN, W_enc, b_enc,
        W0b, Wm1b, Wm2b, Wm3b, W011b, W101b, W111b,
        bm1, bm2, B_a, B_v);
}

// Round 10
// 344.840 us; speedup vs baseline: 1.3711x; 1.0264x over previous
//
#include <hip/hip_runtime.h>
#include <hip/hip_bf16.h>

#define N_NODES 50000
#define N_EDGES 500000
#define DIM_A 128
#define DIM_V 32
#define CHAN 32
#define EB 64            // edges per block in edge kernel
#define SCAN_B 49        // ceil(50000/1024)

typedef __attribute__((ext_vector_type(8))) short short8;
typedef __attribute__((ext_vector_type(8))) unsigned short ushort8;
typedef __attribute__((ext_vector_type(4))) float f32x4;
typedef unsigned short ushort;

#define MFMA __builtin_amdgcn_mfma_f32_16x16x32_bf16

__device__ __forceinline__ ushort f2bf(float x) {
    __hip_bfloat16 h = __float2bfloat16(x);
    return *reinterpret_cast<ushort*>(&h);
}
__device__ __forceinline__ float bf2f(ushort u) {
    union { float f; unsigned int i; } v; v.i = ((unsigned int)u) << 16; return v.f;
}
__device__ __forceinline__ float leaky(float x) {
    return x >= 0.f ? x : 0.1f * x;
}
// pack 4 f32 -> 4 bf16 (2 dwords), bit-exact vs scalar f2bf path.
__device__ __forceinline__ uint2 pk4(f32x4 v) {
    uint2 r;
    r.x = (unsigned)f2bf(v[0]) | ((unsigned)f2bf(v[1]) << 16);
    r.y = (unsigned)f2bf(v[2]) | ((unsigned)f2bf(v[3]) << 16);
    return r;
}

// ---------------- fused prep: convw + node_proj (LDS-staged) + hist ---------
// v8: LN stored in BF16 (v7 computed f32). All LN consumers round to bf16
// immediately, so this costs <=1 bf16-ulp but halves the edge kernel's
// dst-random gather (512->256B/edge) and the LN table (25.6->12.8MB ->
// much better L2/L3 residency).
__global__ __launch_bounds__(256) void prep_kernel(
    const float* __restrict__ x_a, const float* __restrict__ x_v,
    const float* __restrict__ W_L0, const float* __restrict__ W_L1,
    const int* __restrict__ src,
    const float* __restrict__ Wy000, const float* __restrict__ Wy110,
    const float* __restrict__ Wy011, const float* __restrict__ Wy101,
    const float* __restrict__ Wy111,
    const float* __restrict__ Wm1, const float* __restrict__ Wm2,
    const float* __restrict__ Wm3,
    ushort* __restrict__ LNb, int* __restrict__ degS,
    ushort* __restrict__ W0b, ushort* __restrict__ Wm1b,
    ushort* __restrict__ Wm2b, ushort* __restrict__ Wm3b,
    ushort* __restrict__ W011b, ushort* __restrict__ W101b,
    ushort* __restrict__ W111b)
{
    __shared__ __align__(16) float sX[8 * 128];    // x_a rows      (4 KB)
    __shared__ __align__(16) float sV[8 * 96];     // x_v rows      (3 KB)
    __shared__ __align__(16) float sW0[32 * 132];  // W_L0, padded  (16.9 KB)
    __shared__ __align__(16) float sW1[32 * 36];   // W_L1, padded  (4.6 KB)

    const int t = threadIdx.x;
    const int g = blockIdx.x * 256 + t;
    const int n0 = blockIdx.x * 8;

    // --- stage x_a: 8 rows x 128 floats = 256 float4, 1/thread ---
    {
        int nl = t >> 5, k4 = t & 31;
        *(float4*)&sX[nl * 128 + k4 * 4] =
            *(const float4*)(x_a + (size_t)(n0 + nl) * DIM_A + k4 * 4);
    }
    // --- stage x_v: 8 rows x 96 floats = 192 float4 ---
    if (t < 192) {
        int nl = t / 24, j = t - nl * 24;
        *(float4*)&sV[nl * 96 + j * 4] =
            *(const float4*)(x_v + (size_t)(n0 + nl) * 96 + j * 4);
    }
    // --- stage W_L0: 32x128 = 1024 float4, 4/thread ---
#pragma unroll
    for (int i = 0; i < 4; ++i) {
        int idx = i * 256 + t;
        int row = idx >> 5, k4 = idx & 31;
        *(float4*)&sW0[row * 132 + k4 * 4] =
            *(const float4*)(W_L0 + row * DIM_A + k4 * 4);
    }
    // --- stage W_L1: 32x32 = 256 float4, 1/thread ---
    {
        int row = t >> 3, j = t & 7;
        *(float4*)&sW1[row * 36 + j * 4] =
            *(const float4*)(W_L1 + row * DIM_V + j * 4);
    }

    // --- histogram (independent; overlaps staging latency) ---
    if (g < N_EDGES) atomicAdd(&degS[src[g]], 1);

    // --- weight conversion (blocks 0..63) ---
    if (g < 128 * 128) {          // [128][128] matrices, KB=4
        int o = g >> 7, c = g & 127;
        int pi = ((o >> 4) * 4 + (c >> 5)) * 512 + ((c >> 3) & 3) * 128
               + (o & 15) * 8 + (c & 7);
        Wm1b[pi] = f2bf(Wm1[g]);
        Wm2b[pi] = f2bf(Wm2[g]);
        Wm3b[pi] = f2bf(Wm3[g]);
    }
    if (g < 128 * 64) {           // W0cat [128][64], KB=2; c<32 Wy000 else Wy110
        int o = g >> 6, c = g & 63;
        float v = (c < 32) ? Wy000[o * 32 + c] : Wy110[o * 32 + (c - 32)];
        int pi = ((o >> 4) * 2 + (c >> 5)) * 512 + ((c >> 3) & 3) * 128
               + (o & 15) * 8 + (c & 7);
        W0b[pi] = f2bf(v);
    }
    if (g < 32 * 32) {            // [32][32] matrices, KB=1
        int o = g >> 5, c = g & 31;
        int pi = (o >> 4) * 512 + ((c >> 3) & 3) * 128 + (o & 15) * 8 + (c & 7);
        W011b[pi] = f2bf(Wy011[g]);
        W101b[pi] = f2bf(Wy101[g]);
        W111b[pi] = f2bf(Wy111[g]);
    }

    __syncthreads();

    // --- node projection from LDS: LNb[n][128] = [L0(32) | L1(96, c*3+i)] ---
    const int n = t >> 5;
    const int c = t & 31;

    float acc = 0.f;
#pragma unroll 8
    for (int k = 0; k < DIM_A / 4; ++k) {
        float4 x = *(const float4*)&sX[n * 128 + k * 4];
        float4 w = *(const float4*)&sW0[c * 132 + k * 4];
        acc += x.x * w.x + x.y * w.y + x.z * w.z + x.w * w.w;
    }
    LNb[(size_t)(n0 + n) * 128 + c] = f2bf(acc);

    float a0 = 0.f, a1 = 0.f, a2 = 0.f;
#pragma unroll
    for (int dd = 0; dd < DIM_V / 4; ++dd) {
        float4 wv = *(const float4*)&sW1[c * 36 + dd * 4];
        float4 f0 = *(const float4*)&sV[n * 96 + dd * 12 + 0];
        float4 f1 = *(const float4*)&sV[n * 96 + dd * 12 + 4];
        float4 f2 = *(const float4*)&sV[n * 96 + dd * 12 + 8];
        a0 += wv.x * f0.x + wv.y * f0.w + wv.z * f1.z + wv.w * f2.y;
        a1 += wv.x * f0.y + wv.y * f1.x + wv.z * f1.w + wv.w * f2.z;
        a2 += wv.x * f0.z + wv.y * f1.y + wv.z * f2.x + wv.w * f2.w;
    }
    ushort* o = LNb + (size_t)(n0 + n) * 128 + 32 + c * 3;
    o[0] = f2bf(a0); o[1] = f2bf(a1); o[2] = f2bf(a2);
}

// ---------------- scan phase 1: per-1024-block inclusive scan ---------------
__global__ __launch_bounds__(1024) void scan1_kernel(const int* __restrict__ deg,
                                                     int* __restrict__ excl,
                                                     int* __restrict__ bsum)
{
    __shared__ int buf[1024];
    int t = threadIdx.x;
    int i = blockIdx.x * 1024 + t;
    int v = (i < N_NODES) ? deg[i] : 0;
    buf[t] = v;
    __syncthreads();
    for (int off = 1; off < 1024; off <<= 1) {
        int x = (t >= off) ? buf[t - off] : 0;
        __syncthreads();
        buf[t] += x;
        __syncthreads();
    }
    if (i < N_NODES) excl[i] = buf[t] - v;
    if (t == 1023) bsum[blockIdx.x] = buf[1023];
}

// ---------------- scan phase 2: add bsum prefix -> cursor; zero d_out -------
__global__ __launch_bounds__(1024) void scan3_kernel(const int* __restrict__ excl,
                                                     const int* __restrict__ bsum,
                                                     int* __restrict__ cursor,
                                                     f32x4* __restrict__ out4,
                                                     int total4)
{
    __shared__ int sOff;
    int t = threadIdx.x;
    if (t == 0) {
        int s = 0;
#pragma unroll
        for (int k = 0; k < SCAN_B; ++k)
            s += (k < blockIdx.x) ? bsum[k] : 0;
        sOff = s;
    }
    // zero output while the prefix load resolves
    f32x4 z = {0.f, 0.f, 0.f, 0.f};
    for (int i = blockIdx.x * 1024 + t; i < total4; i += SCAN_B * 1024)
        __builtin_nontemporal_store(z, out4 + i);
    __syncthreads();
    int i = blockIdx.x * 1024 + t;
    if (i < N_NODES) cursor[i] = excl[i] + sOff;
}

// ---------------- scatter: build src-sorted packed edge records -------------
__global__ __launch_bounds__(256) void scatter_kernel(
    const int* __restrict__ src, const int* __restrict__ dst,
    const float* __restrict__ r_ij, int* __restrict__ curS,
    float4* __restrict__ edgeS, int* __restrict__ srcIdS)
{
    int i = blockIdx.x * 256 + threadIdx.x;
    if (i < N_EDGES) {
        int s = src[i];
        int p = atomicAdd(&curS[s], 1);
        edgeS[p] = make_float4(r_ij[i * 3 + 0], r_ij[i * 3 + 1], r_ij[i * 3 + 2],
                               __int_as_float(dst[i]));
        srcIdS[p] = s;
    }
}

// ---------------- MFMA edge kernel, fused segmented reduction ---------------
// v8: LN gather in bf16 (4x 16B loads instead of 8, 256B/edge). Otherwise
// v6b structure: operand-swapped MFMAs, packed ds_write_b64 stores, fused
// segmented reduce. LDS exactly 40960 B.
__global__ __launch_bounds__(256, 4) void edge_mfma_kernel(
    const float4* __restrict__ edgeS, const int* __restrict__ srcIdS,
    const ushort* __restrict__ LNb,
    const float* __restrict__ W_enc, const float* __restrict__ b_enc,
    const ushort* __restrict__ W0b, const ushort* __restrict__ Wm1b,
    const ushort* __restrict__ Wm2b, const ushort* __restrict__ Wm3b,
    const ushort* __restrict__ W011b, const ushort* __restrict__ W101b,
    const ushort* __restrict__ W111b,
    const float* __restrict__ bm1, const float* __restrict__ bm2,
    float* __restrict__ B_a, float* __restrict__ B_v)
{
    __shared__ __align__(16) ushort sY0[64 * 72];     // [e][72]: 0..31 y000, 32..63 y110
    __shared__ __align__(16) ushort sRELV[64 * 104];  // [e]: in: re*lv_i; out: psi_v
    __shared__ __align__(16) ushort sACT[64 * 136];   // [e][136] act / final psi_a
    __shared__ __align__(16) float sRS[64 * 4];       // [e]: rsx,rsy,rsz,src-id-bits

    const int t = threadIdx.x;
    const int e0 = blockIdx.x * EB;

    // ---- phase 1: per-edge features -> LDS (wave-row partitioned) ----
    {
        const int e = t >> 2;          // wave w owns e in [16w,16w+16)
        const int p = t & 3;           // 8 channels each
        const int qe = min(e0 + e, N_EDGES - 1);
        f32x4 edv = __builtin_nontemporal_load((const f32x4*)edgeS + qe);
        int sid = __builtin_nontemporal_load(srcIdS + qe);
        float rx = edv[0], ry = edv[1], rz = edv[2];
        int dn = __float_as_int(edv[3]);
        float r = sqrtf(rx * rx + ry * ry + rz * rz);

        float rad[8];
#pragma unroll
        for (int k = 0; k < 8; ++k) {
            float d = (r - (5.0f / 7.0f) * (float)k) * 1.6f;
            rad[k] = __expf(-d * d);
        }
        float n14 = 1.4f * r;
        float ex = __expf(2.f * n14);
        float th = 1.f - 2.f / (ex + 1.f);          // tanh(n14), inf-safe
        float tt = th / fmaxf(n14, 1e-6f);
        float rsx = 1.4f * rx * tt, rsy = 1.4f * ry * tt, rsz = 1.4f * rz * tt;
        if (p == 0) {
            *(float4*)&sRS[e * 4] = make_float4(rsx, rsy, rsz, __int_as_float(sid));
        }

        // LN gather in bf16: la = 1x16B, lv = 3x16B (all 16B-aligned per p)
        const ushort* lnrow = LNb + (size_t)dn * 128;
        ushort8 lau = *(const ushort8*)(lnrow + p * 8);
        float la[8];
#pragma unroll
        for (int j = 0; j < 8; ++j) la[j] = bf2f(lau[j]);
        ushort8 lu0 = *(const ushort8*)(lnrow + 32 + p * 24);
        ushort8 lu1 = *(const ushort8*)(lnrow + 32 + p * 24 + 8);
        ushort8 lu2 = *(const ushort8*)(lnrow + 32 + p * 24 + 16);
        float lv[24];
#pragma unroll
        for (int j = 0; j < 8; ++j) {
            lv[j]      = bf2f(lu0[j]);
            lv[8 + j]  = bf2f(lu1[j]);
            lv[16 + j] = bf2f(lu2[j]);
        }

        ushort8 u000, u110, url[3];
#pragma unroll
        for (int j = 0; j < 8; ++j) {
            int c = p * 8 + j;
            const float4* we = (const float4*)(W_enc + c * 8);
            float4 w0v = we[0], w1v = we[1];
            float re = b_enc[c]
                     + rad[0] * w0v.x + rad[1] * w0v.y + rad[2] * w0v.z + rad[3] * w0v.w
                     + rad[4] * w1v.x + rad[5] * w1v.y + rad[6] * w1v.z + rad[7] * w1v.w;
            float lvx = lv[j * 3 + 0], lvy = lv[j * 3 + 1], lvz = lv[j * 3 + 2];
            float dotv = lvx * rsx + lvy * rsy + lvz * rsz;
            u000[j] = f2bf(la[j] * re);
            u110[j] = f2bf(re * dotv);
            url[0][j] = f2bf(re * lvx);
            url[1][j] = f2bf(re * lvy);
            url[2][j] = f2bf(re * lvz);
        }
        *(ushort8*)&sY0[e * 72 + p * 8]      = u000;
        *(ushort8*)&sY0[e * 72 + 32 + p * 8] = u110;
#pragma unroll
        for (int i = 0; i < 3; ++i)
            *(ushort8*)&sRELV[e * 104 + i * 32 + p * 8] = url[i];
    }

    const int lane = t & 63;
    const int w = t >> 6;
    const int r0 = lane & 15;
    const int quad = lane >> 4;
    const int colw = w * 32;               // this wave's output-channel base

    const short8* W0f   = (const short8*)W0b;
    const short8* Wm1f  = (const short8*)Wm1b;
    const short8* Wm2f  = (const short8*)Wm2b;
    const short8* Wm3f  = (const short8*)Wm3b;
    const short8* W011f = (const short8*)W011b;
    const short8* W101f = (const short8*)W101b;
    const short8* W111f = (const short8*)W111b;

    // prefetch psi0 weights: latency hidden under psi_v MFMAs
    short8 W0r[2][2];
#pragma unroll
    for (int nt2 = 0; nt2 < 2; ++nt2) {
        W0r[nt2][0] = W0f[((w * 2 + nt2) * 2 + 0) * 64 + lane];
        W0r[nt2][1] = W0f[((w * 2 + nt2) * 2 + 1) * 64 + lane];
    }

    // ---- psi_v (wave-local rows; BEFORE any barrier), swapped MFMA ----
    {
        short8 b011[2], b111[2], b101[2];
#pragma unroll
        for (int nt = 0; nt < 2; ++nt) {
            b011[nt] = W011f[nt * 64 + lane];
            b111[nt] = W111f[nt * 64 + lane];
            b101[nt] = W101f[nt * 64 + lane];
        }
        const int arow = w * 16 + r0;
        short8 aY0 = *(const short8*)&sY0[arow * 72 + quad * 8];
        short8 aRL[3];
#pragma unroll
        for (int i = 0; i < 3; ++i)
            aRL[i] = *(const short8*)&sRELV[arow * 104 + i * 32 + quad * 8];
        float4 rsv = *(const float4*)&sRS[arow * 4];

#pragma unroll
        for (int nt = 0; nt < 2; ++nt) {
            __builtin_amdgcn_s_setprio(1);
            f32x4 sA = MFMA(b011[nt], aY0, (f32x4){0.f, 0.f, 0.f, 0.f}, 0, 0, 0);
            f32x4 U[3], T[3];
#pragma unroll
            for (int i = 0; i < 3; ++i) {
                U[i] = MFMA(b111[nt], aRL[i], (f32x4){0.f, 0.f, 0.f, 0.f}, 0, 0, 0);
                T[i] = MFMA(b101[nt], aRL[i], (f32x4){0.f, 0.f, 0.f, 0.f}, 0, 0, 0);
            }
            __builtin_amdgcn_s_setprio(0);
            f32x4 ox, oy, oz;
#pragma unroll
            for (int rr = 0; rr < 4; ++rr) {
                float s = sA[rr];
                float ux = U[0][rr], uy = U[1][rr], uz = U[2][rr];
                ox[rr] = s * rsv.x + T[0][rr] + uy * rsv.z - uz * rsv.y;
                oy[rr] = s * rsv.y + T[1][rr] + uz * rsv.x - ux * rsv.z;
                oz[rr] = s * rsv.z + T[2][rr] + ux * rsv.y - uy * rsv.x;
            }
            int cb = nt * 16 + quad * 4;
            *(uint2*)&sRELV[arow * 104 + 0 * 32 + cb] = pk4(ox);
            *(uint2*)&sRELV[arow * 104 + 1 * 32 + cb] = pk4(oy);
            *(uint2*)&sRELV[arow * 104 + 2 * 32 + cb] = pk4(oz);
        }
    }

    __syncthreads();                       // B1: features + psi_v visible

    // prefetch h1 weights: latency hidden under psi0 MFMAs
    short8 Wm1r[2][4];
#pragma unroll
    for (int nt2 = 0; nt2 < 2; ++nt2)
#pragma unroll
        for (int kb = 0; kb < 4; ++kb)
            Wm1r[nt2][kb] = Wm1f[((w * 2 + nt2) * 4 + kb) * 64 + lane];

    // ---- psi0 = W0cat @ Y0^T (swapped): edge g*16+r0, chans quad*4+rr ----
    f32x4 p0[4][2];
    __builtin_amdgcn_s_setprio(1);
#pragma unroll
    for (int g = 0; g < 4; ++g) {
        short8 a0 = *(const short8*)&sY0[(g * 16 + r0) * 72 + quad * 8];
        short8 a1 = *(const short8*)&sY0[(g * 16 + r0) * 72 + 32 + quad * 8];
#pragma unroll
        for (int nt2 = 0; nt2 < 2; ++nt2) {
            f32x4 acc = {0.f, 0.f, 0.f, 0.f};
            acc = MFMA(W0r[nt2][0], a0, acc, 0, 0, 0);
            acc = MFMA(W0r[nt2][1], a1, acc, 0, 0, 0);
            p0[g][nt2] = acc;
            *(uint2*)&sACT[(g * 16 + r0) * 136 + colw + nt2 * 16 + quad * 4] =
                pk4(acc);
        }
    }
    __builtin_amdgcn_s_setprio(0);
    __syncthreads();                       // B2: psi0 activations ready

    // ---- h1 = leaky(Wm1 @ act^T + bm1), swapped ----
    f32x4 hv[2][4];
    {
        f32x4 bv0 = *(const f32x4*)&bm1[colw + 0 * 16 + quad * 4];
        f32x4 bv1 = *(const f32x4*)&bm1[colw + 1 * 16 + quad * 4];
        __builtin_amdgcn_s_setprio(1);
#pragma unroll
        for (int g = 0; g < 4; ++g) {
            short8 af[4];
#pragma unroll
            for (int kb = 0; kb < 4; ++kb)
                af[kb] = *(const short8*)&sACT[(g * 16 + r0) * 136 + kb * 32 + quad * 8];
            f32x4 aA = bv0, aB = bv1;
#pragma unroll
            for (int kb = 0; kb < 4; ++kb) {
                aA = MFMA(Wm1r[0][kb], af[kb], aA, 0, 0, 0);
                aB = MFMA(Wm1r[1][kb], af[kb], aB, 0, 0, 0);
            }
#pragma unroll
            for (int rr = 0; rr < 4; ++rr) { aA[rr] = leaky(aA[rr]); aB[rr] = leaky(aB[rr]); }
            hv[0][g] = aA; hv[1][g] = aB;
        }
        __builtin_amdgcn_s_setprio(0);
    }
    __syncthreads();                       // B3a: psi0 reads complete

    // prefetch h2 weights during h1 store region
    short8 Wm2r[2][4];
#pragma unroll
    for (int nt2 = 0; nt2 < 2; ++nt2)
#pragma unroll
        for (int kb = 0; kb < 4; ++kb)
            Wm2r[nt2][kb] = Wm2f[((w * 2 + nt2) * 4 + kb) * 64 + lane];

#pragma unroll
    for (int nt2 = 0; nt2 < 2; ++nt2)
#pragma unroll
        for (int g = 0; g < 4; ++g)
            *(uint2*)&sACT[(g * 16 + r0) * 136 + colw + nt2 * 16 + quad * 4] =
                pk4(hv[nt2][g]);
    __syncthreads();                       // B3b: h1 ready

    // ---- h2 = leaky(Wm2 @ act^T + bm2), swapped ----
    {
        f32x4 bv0 = *(const f32x4*)&bm2[colw + 0 * 16 + quad * 4];
        f32x4 bv1 = *(const f32x4*)&bm2[colw + 1 * 16 + quad * 4];
        __builtin_amdgcn_s_setprio(1);
#pragma unroll
        for (int g = 0; g < 4; ++g) {
            short8 af[4];
#pragma unroll
            for (int kb = 0; kb < 4; ++kb)
                af[kb] = *(const short8*)&sACT[(g * 16 + r0) * 136 + kb * 32 + quad * 8];
            f32x4 aA = bv0, aB = bv1;
#pragma unroll
            for (int kb = 0; kb < 4; ++kb) {
                aA = MFMA(Wm2r[0][kb], af[kb], aA, 0, 0, 0);
                aB = MFMA(Wm2r[1][kb], af[kb], aB, 0, 0, 0);
            }
#pragma unroll
            for (int rr = 0; rr < 4; ++rr) { aA[rr] = leaky(aA[rr]); aB[rr] = leaky(aB[rr]); }
            hv[0][g] = aA; hv[1][g] = aB;
        }
        __builtin_amdgcn_s_setprio(0);
    }
    __syncthreads();                       // B4a: h1 reads complete

    // prefetch psi_a weights during h2 store region
    short8 Wm3r[2][4];
#pragma unroll
    for (int nt2 = 0; nt2 < 2; ++nt2)
#pragma unroll
        for (int kb = 0; kb < 4; ++kb)
            Wm3r[nt2][kb] = Wm3f[((w * 2 + nt2) * 4 + kb) * 64 + lane];

#pragma unroll
    for (int nt2 = 0; nt2 < 2; ++nt2)
#pragma unroll
        for (int g = 0; g < 4; ++g)
            *(uint2*)&sACT[(g * 16 + r0) * 136 + colw + nt2 * 16 + quad * 4] =
                pk4(hv[nt2][g]);
    __syncthreads();                       // B4b: h2 ready

    // ---- psi_a = psi0 + Wm3 @ h2^T, swapped ----
    f32x4 fv[2][4];
    __builtin_amdgcn_s_setprio(1);
#pragma unroll
    for (int g = 0; g < 4; ++g) {
        short8 af[4];
#pragma unroll
        for (int kb = 0; kb < 4; ++kb)
            af[kb] = *(const short8*)&sACT[(g * 16 + r0) * 136 + kb * 32 + quad * 8];
#pragma unroll
        for (int nt2 = 0; nt2 < 2; ++nt2) {
            f32x4 acc = {0.f, 0.f, 0.f, 0.f};
#pragma unroll
            for (int kb = 0; kb < 4; ++kb)
                acc = MFMA(Wm3r[nt2][kb], af[kb], acc, 0, 0, 0);
#pragma unroll
            for (int rr = 0; rr < 4; ++rr) acc[rr] += p0[g][nt2][rr];
            fv[nt2][g] = acc;
        }
    }
    __builtin_amdgcn_s_setprio(0);
    __syncthreads();                       // B5a: all h2 reads complete
#pragma unroll
    for (int nt2 = 0; nt2 < 2; ++nt2)
#pragma unroll
        for (int g = 0; g < 4; ++g)
            *(uint2*)&sACT[(g * 16 + r0) * 136 + colw + nt2 * 16 + quad * 4] =
                pk4(fv[nt2][g]);
    __syncthreads();                       // B5b: psi_a (sACT) + psi_v (sRELV)

    // ---- fused segmented reduction over the block's src-sorted edges ----
    {
        const int nE = min(EB, N_EDGES - e0);
        if (t < 224) {
            const bool isA = (t < 128);
            const int j = isA ? t : t - 128;
            const int dcol = j & 31, icol = j >> 5;
            float acc = 0.f;
            int cur = __float_as_int(sRS[3]);   // src id of edge 0
            int runstart = 0;
            for (int el = 0; el < nE; ++el) {
                int s = __float_as_int(sRS[el * 4 + 3]);
                if (s != cur) {
                    float v = 0.1f * acc;
                    float* p = isA ? (B_a + (size_t)cur * 128 + j)
                                   : (B_v + (size_t)cur * 96 + dcol * 3 + icol);
                    if (runstart == 0) atomicAdd(p, v);
                    else __builtin_nontemporal_store(v, p);
                    acc = 0.f; cur = s; runstart = el;
                }
                acc += isA ? bf2f(sACT[el * 136 + j])
                           : bf2f(sRELV[el * 104 + j]);
            }
            float v = 0.1f * acc;              // last run: always boundary
            if (isA) atomicAdd(B_a + (size_t)cur * 128 + j, v);
            else     atomicAdd(B_v + (size_t)cur * 96 + dcol * 3 + icol, v);
        }
    }
}

extern "C" void kernel_launch(void* const* d_in, const int* in_sizes, int n_in,
                              void* d_out, int out_size, void* d_ws, size_t ws_size,
                              hipStream_t stream) {
    const float* x_a   = (const float*)d_in[0];
    const float* x_v   = (const float*)d_in[1];
    const float* r_ij  = (const float*)d_in[2];
    const int*   src   = (const int*)d_in[3];
    const int*   dst   = (const int*)d_in[4];
    const float* W_L0  = (const float*)d_in[5];
    const float* W_L1  = (const float*)d_in[6];
    const float* W_enc = (const float*)d_in[7];
    const float* b_enc = (const float*)d_in[8];
    const float* Wy000 = (const float*)d_in[9];
    const float* Wy110 = (const float*)d_in[10];
    const float* Wy011 = (const float*)d_in[11];
    const float* Wy101 = (const float*)d_in[12];
    const float* Wy111 = (const float*)d_in[13];
    const float* Wm1   = (const float*)d_in[14];
    const float* bm1   = (const float*)d_in[15];
    const float* Wm2   = (const float*)d_in[16];
    const float* bm2   = (const float*)d_in[17];
    const float* Wm3   = (const float*)d_in[18];

    float* out = (float*)d_out;
    float* B_a = out;
    float* B_v = out + (size_t)N_NODES * DIM_A;

    char* w = (char*)d_ws;
    ushort* LNb   = (ushort*)w; w += (size_t)N_NODES * 128 * 2;   // 12.8 MB
    int*   degS   = (int*)w;    w += (size_t)N_NODES * 4;
    int*   curS   = (int*)w;    w += (size_t)N_NODES * 4;
    int*   excl   = (int*)w;    w += (size_t)N_NODES * 4;
    int*   bsum   = (int*)w;    w += 64 * 4;
    int*   srcIdS = (int*)w;    w += (size_t)N_EDGES * 4;
    float4* edgeS = (float4*)w; w += (size_t)N_EDGES * 16;
    ushort* W0b   = (ushort*)w; w += 128 * 64 * 2;
    ushort* Wm1b  = (ushort*)w; w += 128 * 128 * 2;
    ushort* Wm2b  = (ushort*)w; w += 128 * 128 * 2;
    ushort* Wm3b  = (ushort*)w; w += 128 * 128 * 2;
    ushort* W011b = (ushort*)w; w += 32 * 32 * 2;
    ushort* W101b = (ushort*)w; w += 32 * 32 * 2;
    ushort* W111b = (ushort*)w; w += 32 * 32 * 2;

    (void)hipMemsetAsync(degS, 0, N_NODES * sizeof(int), stream);

    prep_kernel<<<(N_NODES + 7) / 8, 256, 0, stream>>>(
        x_a, x_v, W_L0, W_L1, src,
        Wy000, Wy110, Wy011, Wy101, Wy111, Wm1, Wm2, Wm3,
        LNb, degS, W0b, Wm1b, Wm2b, Wm3b, W011b, W101b, W111b);

    scan1_kernel<<<SCAN_B, 1024, 0, stream>>>(degS, excl, bsum);
    scan3_kernel<<<SCAN_B, 1024, 0, stream>>>(excl, bsum, curS,
                                              (f32x4*)d_out,
                                              (N_NODES * 224) / 4);

    scatter_kernel<<<(N_EDGES + 255) / 256, 256, 0, stream>>>(src, dst, r_ij, curS,
                                                              edgeS, srcIdS);

    edge_mfma_kernel<<<(N_EDGES + EB - 1) / EB, 256, 0, stream>>>(
        edgeS, srcIdS, LNb, W_enc, b_enc,
        W0b, Wm1b, Wm2b, Wm3b, W011b, W101b, W111b,
        bm1, bm2, B_a, B_v);
}